// Round 9
// baseline (489.824 us; speedup 1.0000x reference)
//
#include <hip/hip_runtime.h>

// RGATNetwork: 2x RGATConv (R=4, H=4, C=32, HC=128, F_E=16) on N=50k nodes, E=800k edges.
// R19 = R16 base (best, 432us; R17/R18 record experiments both regressed and are
// reverted) + qkx(L2) fused into agg1's epilogue:
//  - agg1's quarter already holds the full post-ReLU h row in registers; it now
//    computes q3/k3 per relation (wqk3 read from global, L2-hot; 4-level shfl_xor
//    quarter reduce; lane 0 writes float4s) into SEPARATE qn2/kn2 (qn/kn is still
//    being read by concurrent blocks).
//  - hbuf is DELETED entirely (25.6MB write + 25.6MB read gone).
//  - p2 becomes pure proj(L2) (grid 3910 -> 3128 blocks).
// R18 lesson recorded: scatter write traffic scales with record footprint after L2
// line merging (~4-8 same-dst narrow records share a line) — NOT "one line per edge";
// widening records adds real write + write-allocate traffic.

#define NEG_SLOPE 0.2f
#define SOFT_EPS 1e-16f

typedef __attribute__((ext_vector_type(8))) short bf16x8;
typedef __attribute__((ext_vector_type(4))) float f32x4;
typedef __attribute__((ext_vector_type(4))) unsigned short u16x4;
typedef __attribute__((ext_vector_type(4))) _Float16 half4;
typedef __attribute__((ext_vector_type(8))) _Float16 half8;

__device__ __forceinline__ void bf16split(float f, unsigned short& h, unsigned short& l) {
  unsigned u = __float_as_uint(f);
  unsigned r = u + 0x7FFFu + ((u >> 16) & 1u);
  h = (unsigned short)(r >> 16);
  float fh = __uint_as_float(((unsigned)h) << 16);
  float d = f - fh;
  unsigned u2 = __float_as_uint(d);
  unsigned r2 = u2 + 0x7FFFu + ((u2 >> 16) & 1u);
  l = (unsigned short)(r2 >> 16);
}

// ================= fused-preprocess bodies =================

__device__ __forceinline__ void hist_body(int id, const int* __restrict__ dst,
                                          int* __restrict__ deg, int E) {
  int e = id * 256 + (int)threadIdx.x;
  if (e < E) atomicAdd(&deg[dst[e]], 1);
}

__device__ __forceinline__ void convx_body(int id, const float* __restrict__ in,
                                           unsigned short* __restrict__ hi,
                                           unsigned short* __restrict__ lo, int total8) {
  int i = id * 256 + (int)threadIdx.x;
  if (i >= total8) return;
  const float4* p = (const float4*)in + (size_t)i * 2;
  float4 a = p[0], b = p[1];
  float v[8] = {a.x, a.y, a.z, a.w, b.x, b.y, b.z, b.w};
  bf16x8 hv, lv;
#pragma unroll
  for (int j = 0; j < 8; ++j) {
    unsigned short h, l;
    bf16split(v[j], h, l);
    hv[j] = (short)h; lv[j] = (short)l;
  }
  *(bf16x8*)(hi + (size_t)i * 8) = hv;
  *(bf16x8*)(lo + (size_t)i * 8) = lv;
}

// fragment-major w: element index = r*16384 + (((ot*4+kc)*4+q)*16 + c)*8 + j
// where o = ot*16+c, f = kc*32 + q*8 + j.
__device__ __forceinline__ void convw_body(int idx, const float* __restrict__ w1,
                                           const float* __restrict__ w3,
                                           unsigned short* __restrict__ wF1h,
                                           unsigned short* __restrict__ wF1l,
                                           unsigned short* __restrict__ wF3h,
                                           unsigned short* __restrict__ wF3l) {
  if (idx >= 131072) return;
  int L = idx >> 16;
  int rem = idx & 65535;
  int r = rem >> 14, rem2 = rem & 16383, f = rem2 >> 7, o = rem2 & 127;
  const float* w = L ? w3 : w1;
  unsigned short* dh = L ? wF3h : wF1h;
  unsigned short* dl = L ? wF3l : wF1l;
  float v = w[(r * 128 + f) * 128 + o];
  unsigned short h, l;
  bf16split(v, h, l);
  int ot = o >> 4, c = o & 15, kc = f >> 5, q = (f >> 3) & 3, j = f & 7;
  int di = r * 16384 + ((((ot * 4 + kc) * 4 + q) * 16 + c) * 8 + j);
  dh[di] = h;
  dl[di] = l;
}

__device__ __forceinline__ void wqk_body(int idx, const float* __restrict__ w1,
                                         const float* __restrict__ q1, const float* __restrict__ k1,
                                         const float* __restrict__ w3, const float* __restrict__ q3,
                                         const float* __restrict__ k3, float* __restrict__ wqk) {
  if (idx >= 8192) return;
  int L = idx >> 12, rem = idx & 4095;
  int r = rem >> 10, rem2 = rem & 1023, f = rem2 >> 3, j = rem2 & 7;
  const float* w = L ? w3 : w1;
  const float* qk = (j < 4) ? (L ? q3 : q1) : (L ? k3 : k1);
  int h = j & 3;
  const float* wrow = w + (r * 128 + f) * 128;
  float acc = 0.f;
  for (int o = 0; o < 128; ++o) acc += wrow[o] * qk[o * 4 + h];
  wqk[idx] = acc;
}

__device__ __forceinline__ void lee_body(const float* __restrict__ le1, const float* __restrict__ e1,
                                         const float* __restrict__ le3, const float* __restrict__ e3,
                                         float* __restrict__ lee) {
  int t = threadIdx.x;
  if (t >= 128) return;
  const float* le = (t < 64) ? le1 : le3;
  const float* ee = (t < 64) ? e1 : e3;
  int u = t & 63, f = u >> 2, h = u & 3;
  float acc = 0.f;
  for (int o = 0; o < 128; ++o) acc += le[f * 128 + o] * ee[o * 4 + h];
  lee[t] = acc;
}

// pre: [0,nAB): parity-interleaved hist/convx; tail: convw(512) | wqk(32) | lee(1)
__global__ __launch_bounds__(256) void pre_kernel(
    const int* __restrict__ dst, int* __restrict__ deg, int E,
    const float* __restrict__ x, unsigned short* __restrict__ xhi,
    unsigned short* __restrict__ xlo, int total8,
    const float* __restrict__ w1, const float* __restrict__ q1, const float* __restrict__ k1,
    const float* __restrict__ w3, const float* __restrict__ q3, const float* __restrict__ k3,
    float* __restrict__ wqk,
    const float* __restrict__ le1, const float* __restrict__ e1,
    const float* __restrict__ le3, const float* __restrict__ e3, float* __restrict__ lee,
    unsigned short* __restrict__ wF1h, unsigned short* __restrict__ wF1l,
    unsigned short* __restrict__ wF3h, unsigned short* __restrict__ wF3l,
    int nAB, int eb, int cxb) {
  int bid = blockIdx.x;
  if (bid < nAB) {
    int id = bid >> 1;
    if (bid & 1) {
      if (id < eb) hist_body(id, dst, deg, E);
    } else {
      if (id < cxb) convx_body(id, x, xhi, xlo, total8);
    }
  } else {
    int b2 = bid - nAB;
    if (b2 < 512) {
      convw_body(b2 * 256 + (int)threadIdx.x, w1, w3, wF1h, wF1l, wF3h, wF3l);
    } else if (b2 < 544) {
      wqk_body((b2 - 512) * 256 + (int)threadIdx.x, w1, q1, k1, w3, q3, k3, wqk);
    } else {
      lee_body(le1, e1, le3, e3, lee);
    }
  }
}

// ================= CSR scans =================

__global__ __launch_bounds__(256) void scanA_kernel(const int* __restrict__ deg,
                                                    int* __restrict__ bsum, int N) {
  int b = blockIdx.x, t = threadIdx.x;
  int base = b * 1024 + t * 4;
  int s = 0;
#pragma unroll
  for (int j = 0; j < 4; ++j) {
    int i = base + j;
    if (i < N) s += deg[i];
  }
#pragma unroll
  for (int o = 1; o < 64; o <<= 1) s += __shfl_xor(s, o);
  __shared__ int wsum[4];
  if ((t & 63) == 0) wsum[t >> 6] = s;
  __syncthreads();
  if (t == 0) bsum[b] = wsum[0] + wsum[1] + wsum[2] + wsum[3];
}

__global__ __launch_bounds__(256) void scanB_kernel(const int* __restrict__ bsum,
                                                    int* __restrict__ boff,
                                                    int* __restrict__ row_start,
                                                    int nb, int N) {
  int t = threadIdx.x;
  int v = (t < nb) ? bsum[t] : 0;
  int inc = v;
#pragma unroll
  for (int o = 1; o < 64; o <<= 1) {
    int u = __shfl_up(inc, o);
    if ((t & 63) >= o) inc += u;
  }
  __shared__ int wt[4];
  if ((t & 63) == 63) wt[t >> 6] = inc;
  __syncthreads();
  int add = 0;
  for (int wv = 0; wv < (t >> 6); ++wv) add += wt[wv];
  inc += add;
  if (t < nb) boff[t] = inc - v;
  if (t == 255) row_start[N] = inc;
}

__global__ __launch_bounds__(256) void scanC_kernel(const int* __restrict__ deg,
                                                    const int* __restrict__ boff,
                                                    int* __restrict__ row_start,
                                                    int* __restrict__ cursor, int N) {
  int b = blockIdx.x, t = threadIdx.x;
  int base = b * 1024 + t * 4;
  int d[4];
  int s = 0;
#pragma unroll
  for (int j = 0; j < 4; ++j) {
    int i = base + j;
    d[j] = (i < N) ? deg[i] : 0;
    s += d[j];
  }
  int inc = s;
#pragma unroll
  for (int o = 1; o < 64; o <<= 1) {
    int u = __shfl_up(inc, o);
    if ((t & 63) >= o) inc += u;
  }
  __shared__ int wt[4];
  if ((t & 63) == 63) wt[t >> 6] = inc;
  __syncthreads();
  int add = boff[b];
  for (int wv = 0; wv < (t >> 6); ++wv) add += wt[wv];
  int off = add + inc - s;
#pragma unroll
  for (int j = 0; j < 4; ++j) {
    int i = base + j;
    if (i < N) {
      row_start[i] = off;
      cursor[i] = off;
      off += d[j];
    }
  }
}

// ================= sc9 bodies =================

__device__ __forceinline__ void scatter_body(int id, const int* __restrict__ src,
                                             const int* __restrict__ dst,
                                             const int* __restrict__ et,
                                             int* __restrict__ cursor,
                                             int4* __restrict__ es, int E) {
  int e = id * 256 + (int)threadIdx.x;
  if (e >= E) return;
  int d = dst[e];
  int pos = atomicAdd(&cursor[d], 1);
  es[pos] = make_int4(src[e], d, et[e], e);
}

// qkx: qn/kn from xin via folded wqk; 64 nodes/block; smem = 16512 B (wqk stage only).
__device__ __forceinline__ void qkx_body(int nbid, char* smem, const float* __restrict__ xin,
                                         const float* __restrict__ wqk, float* __restrict__ qn,
                                         float* __restrict__ kn, int N) {
  float* swqk = (float*)smem;  // 4*1032 floats
  int t = threadIdx.x;
#pragma unroll
  for (int j = 0; j < 16; ++j) {
    int i = j * 256 + t;
    swqk[(i >> 10) * 1032 + (i & 1023)] = wqk[i];
  }
  __syncthreads();
  int nb = nbid * 64;
  int rl = t >> 2, r = t & 3;
  int n = nb + rl;
  int nc = n < N ? n : N - 1;
  const float4* xr = (const float4*)(xin + (size_t)nc * 128);
  const float* wb = swqk + r * 1032;
  float aq0 = 0, aq1 = 0, aq2 = 0, aq3 = 0;
  float ak0 = 0, ak1 = 0, ak2 = 0, ak3 = 0;
#pragma unroll 4
  for (int f4 = 0; f4 < 32; ++f4) {
    float4 xv = xr[f4];
    const float* w0 = wb + f4 * 32;
    float4 qa = *(const float4*)(w0);
    float4 ka = *(const float4*)(w0 + 4);
    float4 qb = *(const float4*)(w0 + 8);
    float4 kb = *(const float4*)(w0 + 12);
    float4 qc = *(const float4*)(w0 + 16);
    float4 kc = *(const float4*)(w0 + 20);
    float4 qd = *(const float4*)(w0 + 24);
    float4 kd = *(const float4*)(w0 + 28);
    aq0 += xv.x * qa.x + xv.y * qb.x + xv.z * qc.x + xv.w * qd.x;
    aq1 += xv.x * qa.y + xv.y * qb.y + xv.z * qc.y + xv.w * qd.y;
    aq2 += xv.x * qa.z + xv.y * qb.z + xv.z * qc.z + xv.w * qd.z;
    aq3 += xv.x * qa.w + xv.y * qb.w + xv.z * qc.w + xv.w * qd.w;
    ak0 += xv.x * ka.x + xv.y * kb.x + xv.z * kc.x + xv.w * kd.x;
    ak1 += xv.x * ka.y + xv.y * kb.y + xv.z * kc.y + xv.w * kd.y;
    ak2 += xv.x * ka.z + xv.y * kb.z + xv.z * kc.z + xv.w * kd.z;
    ak3 += xv.x * ka.w + xv.y * kb.w + xv.z * kc.w + xv.w * kd.w;
  }
  if (n < N) {
    *(float4*)(qn + ((size_t)r * N + n) * 4) = make_float4(aq0, aq1, aq2, aq3);
    *(float4*)(kn + ((size_t)r * N + n) * 4) = make_float4(ak0, ak1, ak2, ak3);
  }
}

// proj: MFMA per-relation projection; HALF-tile (4 of 8 ot) staged in 32KB LDS from
// the fragment-major global layout (contiguous 16KB copy per hi/lo).
// pid: r = pid&3, half = (pid>>2)&1, node block = (pid>>3)*128.
__device__ __forceinline__ void proj_body(int pid, char* smem,
                                          const unsigned short* __restrict__ xhi,
                                          const unsigned short* __restrict__ xlo,
                                          const unsigned short* __restrict__ wFh,
                                          const unsigned short* __restrict__ wFl,
                                          _Float16* __restrict__ xwh, int N) {
  bf16x8* wl_h = (bf16x8*)smem;   // 1024 units, 16KB
  bf16x8* wl_l = wl_h + 1024;     // 16KB
  int r = pid & 3;
  int h0 = (pid >> 2) & 1;
  int nb = (pid >> 3) * 128;
  int t = threadIdx.x;
  const bf16x8* srcH = (const bf16x8*)(wFh + r * 16384) + h0 * 1024;
  const bf16x8* srcL = (const bf16x8*)(wFl + r * 16384) + h0 * 1024;
#pragma unroll
  for (int j = 0; j < 4; ++j) {
    int i = j * 256 + t;
    wl_h[i] = srcH[i];
    wl_l[i] = srcL[i];
  }
  __syncthreads();

  int wv = t >> 6;
  int lane = t & 63;
  int c = lane & 15, q = lane >> 4;
  int nodebase = nb + wv * 32;
  int n0 = nodebase + c;
  int n1 = nodebase + 16 + c;
  int n0c = n0 < N ? n0 : N - 1;
  int n1c = n1 < N ? n1 : N - 1;

  f32x4 acc[4][2];
#pragma unroll
  for (int ot = 0; ot < 4; ++ot)
#pragma unroll
    for (int nt = 0; nt < 2; ++nt) acc[ot][nt] = (f32x4){0.f, 0.f, 0.f, 0.f};

  bf16x8 xb[2][4];
  {
    int k0 = q * 8;
    xb[0][0] = *(const bf16x8*)(xhi + (size_t)n0c * 128 + k0);
    xb[0][1] = *(const bf16x8*)(xlo + (size_t)n0c * 128 + k0);
    xb[0][2] = *(const bf16x8*)(xhi + (size_t)n1c * 128 + k0);
    xb[0][3] = *(const bf16x8*)(xlo + (size_t)n1c * 128 + k0);
  }
#pragma unroll
  for (int kc = 0; kc < 4; ++kc) {
    if (kc < 3) {
      int k0 = (kc + 1) * 32 + q * 8;
      xb[(kc + 1) & 1][0] = *(const bf16x8*)(xhi + (size_t)n0c * 128 + k0);
      xb[(kc + 1) & 1][1] = *(const bf16x8*)(xlo + (size_t)n0c * 128 + k0);
      xb[(kc + 1) & 1][2] = *(const bf16x8*)(xhi + (size_t)n1c * 128 + k0);
      xb[(kc + 1) & 1][3] = *(const bf16x8*)(xlo + (size_t)n1c * 128 + k0);
    }
    bf16x8 b0h = xb[kc & 1][0], b0l = xb[kc & 1][1];
    bf16x8 b1h = xb[kc & 1][2], b1l = xb[kc & 1][3];
#pragma unroll
    for (int ot = 0; ot < 4; ++ot) {
      int fi = ((ot * 4 + kc) * 4 + q) * 16 + c;
      bf16x8 ah = wl_h[fi];
      bf16x8 al = wl_l[fi];
      acc[ot][0] = __builtin_amdgcn_mfma_f32_16x16x32_bf16(ah, b0h, acc[ot][0], 0, 0, 0);
      acc[ot][0] = __builtin_amdgcn_mfma_f32_16x16x32_bf16(ah, b0l, acc[ot][0], 0, 0, 0);
      acc[ot][0] = __builtin_amdgcn_mfma_f32_16x16x32_bf16(al, b0h, acc[ot][0], 0, 0, 0);
      acc[ot][1] = __builtin_amdgcn_mfma_f32_16x16x32_bf16(ah, b1h, acc[ot][1], 0, 0, 0);
      acc[ot][1] = __builtin_amdgcn_mfma_f32_16x16x32_bf16(ah, b1l, acc[ot][1], 0, 0, 0);
      acc[ot][1] = __builtin_amdgcn_mfma_f32_16x16x32_bf16(al, b1h, acc[ot][1], 0, 0, 0);
    }
  }

#pragma unroll
  for (int nt = 0; nt < 2; ++nt) {
    int n = nodebase + nt * 16 + c;
    if (n < N) {
      _Float16* basep = xwh + ((size_t)r * N + n) * 128 + h0 * 64 + q * 4;
#pragma unroll
      for (int ot = 0; ot < 4; ++ot) {
        f32x4 a = acc[ot][nt];
        half4 hv;
        hv[0] = (_Float16)a.x; hv[1] = (_Float16)a.y;
        hv[2] = (_Float16)a.z; hv[3] = (_Float16)a.w;
        *(half4*)(basep + ot * 16) = hv;
      }
    }
  }
}

// sc9: groups of 9 blocks = 4 scatter + 1 qkx(L1) + 4 proj(L1).  smem = 32768 B.
__global__ __launch_bounds__(256) void sc9_kernel(
    const int* __restrict__ src, const int* __restrict__ dst, const int* __restrict__ et,
    int* __restrict__ cursor, int4* __restrict__ es, int E,
    const float* __restrict__ xin, const float* __restrict__ wqk,
    float* __restrict__ qn, float* __restrict__ kn, int N, int qxb,
    const unsigned short* __restrict__ xhi, const unsigned short* __restrict__ xlo,
    const unsigned short* __restrict__ wFh, const unsigned short* __restrict__ wFl,
    _Float16* __restrict__ xwh, int pjb) {
  extern __shared__ char smem[];
  int bid = blockIdx.x;
  int g = bid / 9, r9 = bid - g * 9;
  if (r9 < 4) {
    scatter_body(g * 4 + r9, src, dst, et, cursor, es, E);
  } else if (r9 == 4) {
    if (g < qxb) qkx_body(g, smem, xin, wqk, qn, kn, N);
  } else {
    int id = g * 4 + (r9 - 5);
    if (id < pjb) proj_body(id, smem, xhi, xlo, wFh, wFl, xwh, N);
  }
}

// ================= ek2 (standalone) =================

__global__ __launch_bounds__(256) void ek2_kernel(
    const int4* __restrict__ es, const float* __restrict__ ea,
    const float* __restrict__ lee, float* __restrict__ eks1,
    float* __restrict__ eks3, int E) {
  __shared__ float sl[128];
  if (threadIdx.x < 128) sl[threadIdx.x] = lee[threadIdx.x];
  __syncthreads();
  int i = blockIdx.x * 256 + (int)threadIdx.x;
  if (i >= E) return;
  int eid = es[i].w;
  const float4* a4 = (const float4*)(ea + (size_t)eid * 16);
  float a1[4] = {0, 0, 0, 0}, a3[4] = {0, 0, 0, 0};
#pragma unroll
  for (int ii = 0; ii < 4; ++ii) {
    float4 v = a4[ii];
    int f = ii * 4;
#pragma unroll
    for (int h = 0; h < 4; ++h) {
      a1[h] += v.x * sl[f * 4 + h] + v.y * sl[(f + 1) * 4 + h] +
               v.z * sl[(f + 2) * 4 + h] + v.w * sl[(f + 3) * 4 + h];
      a3[h] += v.x * sl[64 + f * 4 + h] + v.y * sl[64 + (f + 1) * 4 + h] +
               v.z * sl[64 + (f + 2) * 4 + h] + v.w * sl[64 + (f + 3) * 4 + h];
    }
  }
  *(float4*)(eks1 + (size_t)i * 4) = make_float4(a1[0], a1[1], a1[2], a1[3]);
  *(float4*)(eks3 + (size_t)i * 4) = make_float4(a3[0], a3[1], a3[2], a3[3]);
}

// projL2: pure proj(L2).  smem = 32768 B.
__global__ __launch_bounds__(256) void projL2_kernel(
    const unsigned short* __restrict__ xhi, const unsigned short* __restrict__ xlo,
    const unsigned short* __restrict__ wFh, const unsigned short* __restrict__ wFl,
    _Float16* __restrict__ xwh, int N, int pjb) {
  extern __shared__ char smem[];
  int id = blockIdx.x;
  if (id < pjb) proj_body(id, smem, xhi, xlo, wFh, wFl, xwh, N);
}

// ================= fused softmax-aggregate =================

__device__ __forceinline__ float4 edge_alpha(const int4* __restrict__ es,
                                             const float* __restrict__ qn,
                                             const float* __restrict__ kn,
                                             const float* __restrict__ eks,
                                             int i, int d, int N) {
  int4 v = es[i];
  float4 kv = *(const float4*)(kn + (v.z * N + v.x) * 4);
  float4 ev = ((const float4*)eks)[i];
  float4 q4 = *(const float4*)(qn + (v.z * N + d) * 4);
  float4 a = make_float4(q4.x + kv.x + ev.x, q4.y + kv.y + ev.y,
                         q4.z + kv.z + ev.z, q4.w + kv.w + ev.w);
  a.x = a.x > 0.f ? a.x : NEG_SLOPE * a.x;
  a.y = a.y > 0.f ? a.y : NEG_SLOPE * a.y;
  a.z = a.z > 0.f ? a.z : NEG_SLOPE * a.z;
  a.w = a.w > 0.f ? a.w : NEG_SLOPE * a.w;
  return a;
}

__device__ __forceinline__ float4 max4(float4 a, float4 b) {
  return make_float4(fmaxf(a.x, b.x), fmaxf(a.y, b.y), fmaxf(a.z, b.z), fmaxf(a.w, b.w));
}

// One 16-lane quarter per dst. Sweep A: branchless clamped 4-chain loads (deg<=64),
// cndmask validity. Pass 2: 4 independent edge chains per iteration.
// concat==1 (layer 1): epilogue also computes q3/k3 per relation from the register
// h row (fused qkx-L2): per-lane 8x8 partials from global wqk3 (L2-hot), 4-level
// shfl_xor quarter reduce, lane 0 writes to qn2/kn2 (NOT qn/kn - still being read).
__global__ __launch_bounds__(256) void agg_kernel(
    const int4* __restrict__ es, const int* __restrict__ row_start,
    const float* __restrict__ qn, const float* __restrict__ kn,
    const float* __restrict__ eks, float* __restrict__ alpha_s,
    const _Float16* __restrict__ xwh, const float* __restrict__ bias,
    float* __restrict__ out, unsigned short* __restrict__ xhi,
    unsigned short* __restrict__ xlo,
    float* __restrict__ qn2, float* __restrict__ kn2,
    const float* __restrict__ wqk3, int N, int concat) {
  int d = blockIdx.x * 16 + (threadIdx.x >> 4);
  if (d >= N) return;
  int ql = threadIdx.x & 15;
  int rs = row_start[d], re = row_start[d + 1];
  int deg = re - rs;
  int h = ql >> 2;

  float acc[8];
#pragma unroll
  for (int j = 0; j < 8; ++j) acc[j] = 0.f;
  float rden = 0.f;

  if (deg > 0) {
    float4 m = make_float4(-1e30f, -1e30f, -1e30f, -1e30f);
    float4 ar0 = m, ar1 = m, ar2 = m, ar3 = m;
    bool fast = (deg <= 64);
    bool v0 = ql < deg, v1 = 16 + ql < deg, v2 = 32 + ql < deg, v3 = 48 + ql < deg;
    if (fast) {
      int dm1 = deg - 1;
      int o0 = v0 ? ql : dm1;
      int o1 = v1 ? 16 + ql : dm1;
      int o2 = v2 ? 32 + ql : dm1;
      int o3 = v3 ? 48 + ql : dm1;
      float4 a0 = edge_alpha(es, qn, kn, eks, rs + o0, d, N);
      float4 a1 = edge_alpha(es, qn, kn, eks, rs + o1, d, N);
      float4 a2 = edge_alpha(es, qn, kn, eks, rs + o2, d, N);
      float4 a3 = edge_alpha(es, qn, kn, eks, rs + o3, d, N);
      if (v0) { ar0 = a0; m = max4(m, a0); }
      if (v1) { ar1 = a1; m = max4(m, a1); }
      if (v2) { ar2 = a2; m = max4(m, a2); }
      if (v3) { ar3 = a3; m = max4(m, a3); }
    } else {
      for (int i = rs + ql; i < re; i += 16) {
        float4 a = edge_alpha(es, qn, kn, eks, i, d, N);
        ((float4*)alpha_s)[i] = a;
        m = max4(m, a);
      }
    }
#pragma unroll
    for (int o = 1; o < 16; o <<= 1) {
      m.x = fmaxf(m.x, __shfl_xor(m.x, o));
      m.y = fmaxf(m.y, __shfl_xor(m.y, o));
      m.z = fmaxf(m.z, __shfl_xor(m.z, o));
      m.w = fmaxf(m.w, __shfl_xor(m.w, o));
    }

    float4 s = make_float4(0.f, 0.f, 0.f, 0.f);
    if (fast) {
#define SWEEPB(V, AR, OFF)                                                   \
      if (V) {                                                               \
        float4 e4 = make_float4(__expf(AR.x - m.x), __expf(AR.y - m.y),      \
                                __expf(AR.z - m.z), __expf(AR.w - m.w));     \
        ((float4*)alpha_s)[rs + OFF + ql] = e4;                              \
        s.x += e4.x; s.y += e4.y; s.z += e4.z; s.w += e4.w;                  \
      }
      SWEEPB(v0, ar0, 0)
      SWEEPB(v1, ar1, 16)
      SWEEPB(v2, ar2, 32)
      SWEEPB(v3, ar3, 48)
#undef SWEEPB
    } else {
      for (int i = rs + ql; i < re; i += 16) {
        float4 a = ((const float4*)alpha_s)[i];
        float4 e4 = make_float4(__expf(a.x - m.x), __expf(a.y - m.y),
                                __expf(a.z - m.z), __expf(a.w - m.w));
        ((float4*)alpha_s)[i] = e4;
        s.x += e4.x; s.y += e4.y; s.z += e4.z; s.w += e4.w;
      }
    }
#pragma unroll
    for (int o = 1; o < 16; o <<= 1) {
      s.x += __shfl_xor(s.x, o); s.y += __shfl_xor(s.y, o);
      s.z += __shfl_xor(s.z, o); s.w += __shfl_xor(s.w, o);
    }
    float smh = (h == 0) ? s.x : (h == 1) ? s.y : (h == 2) ? s.z : s.w;
    rden = 1.f / (smh + SOFT_EPS);

    // pass 2: 4 independent edge chains per iteration
    int e = rs;
    for (; e + 4 <= re; e += 4) {
      int4 a0 = es[e];
      int4 a1 = es[e + 1];
      int4 a2 = es[e + 2];
      int4 a3 = es[e + 3];
      float w0 = alpha_s[e * 4 + h];
      float w1 = alpha_s[(e + 1) * 4 + h];
      float w2 = alpha_s[(e + 2) * 4 + h];
      float w3 = alpha_s[(e + 3) * 4 + h];
      half8 x0 = *(const half8*)(xwh + (a0.z * N + a0.x) * 128 + ql * 8);
      half8 x1 = *(const half8*)(xwh + (a1.z * N + a1.x) * 128 + ql * 8);
      half8 x2 = *(const half8*)(xwh + (a2.z * N + a2.x) * 128 + ql * 8);
      half8 x3 = *(const half8*)(xwh + (a3.z * N + a3.x) * 128 + ql * 8);
#pragma unroll
      for (int j = 0; j < 8; ++j) {
        acc[j] = fmaf((float)x0[j], w0, acc[j]);
        acc[j] = fmaf((float)x1[j], w1, acc[j]);
        acc[j] = fmaf((float)x2[j], w2, acc[j]);
        acc[j] = fmaf((float)x3[j], w3, acc[j]);
      }
    }
    for (; e < re; ++e) {
      int4 a0 = es[e];
      float w0 = alpha_s[e * 4 + h];
      half8 x0 = *(const half8*)(xwh + (a0.z * N + a0.x) * 128 + ql * 8);
#pragma unroll
      for (int j = 0; j < 8; ++j) acc[j] = fmaf((float)x0[j], w0, acc[j]);
    }
  }
#pragma unroll
  for (int j = 0; j < 8; ++j) acc[j] *= rden;

  if (concat) {  // layer 1: h = relu(agg+b1) -> xhi/xlo (bf16 split) + fused qkx(L2)
    float4 b0 = ((const float4*)bias)[ql * 2];
    float4 b1 = ((const float4*)bias)[ql * 2 + 1];
    float v[8] = {acc[0] + b0.x, acc[1] + b0.y, acc[2] + b0.z, acc[3] + b0.w,
                  acc[4] + b1.x, acc[5] + b1.y, acc[6] + b1.z, acc[7] + b1.w};
    u16x4 hv0, lv0, hv1, lv1;
#pragma unroll
    for (int j = 0; j < 8; ++j) {
      v[j] = v[j] > 0.f ? v[j] : 0.f;
      unsigned short hh, ll;
      bf16split(v[j], hh, ll);
      if (j < 4) { hv0[j] = hh; lv0[j] = ll; }
      else { hv1[j - 4] = hh; lv1[j - 4] = ll; }
    }
    *(u16x4*)(xhi + (size_t)d * 128 + ql * 8) = hv0;
    *(u16x4*)(xhi + (size_t)d * 128 + ql * 8 + 4) = hv1;
    *(u16x4*)(xlo + (size_t)d * 128 + ql * 8) = lv0;
    *(u16x4*)(xlo + (size_t)d * 128 + ql * 8 + 4) = lv1;

    // fused qkx(L2): wqk3[r][f][o], f = ql*8 + j, o in [0,8) (q heads 0-3, k heads 4-7)
#pragma unroll
    for (int r = 0; r < 4; ++r) {
      const float* wb = wqk3 + r * 1024 + ql * 64;
      float p0 = 0, p1 = 0, p2 = 0, p3 = 0, p4 = 0, p5 = 0, p6 = 0, p7 = 0;
#pragma unroll
      for (int j = 0; j < 8; ++j) {
        float hv = v[j];
        float4 wa = *(const float4*)(wb + j * 8);
        float4 wk = *(const float4*)(wb + j * 8 + 4);
        p0 = fmaf(hv, wa.x, p0); p1 = fmaf(hv, wa.y, p1);
        p2 = fmaf(hv, wa.z, p2); p3 = fmaf(hv, wa.w, p3);
        p4 = fmaf(hv, wk.x, p4); p5 = fmaf(hv, wk.y, p5);
        p6 = fmaf(hv, wk.z, p6); p7 = fmaf(hv, wk.w, p7);
      }
#pragma unroll
      for (int o = 1; o < 16; o <<= 1) {
        p0 += __shfl_xor(p0, o); p1 += __shfl_xor(p1, o);
        p2 += __shfl_xor(p2, o); p3 += __shfl_xor(p3, o);
        p4 += __shfl_xor(p4, o); p5 += __shfl_xor(p5, o);
        p6 += __shfl_xor(p6, o); p7 += __shfl_xor(p7, o);
      }
      if (ql == 0) {
        *(float4*)(qn2 + ((size_t)r * N + d) * 4) = make_float4(p0, p1, p2, p3);
        *(float4*)(kn2 + ((size_t)r * N + d) * 4) = make_float4(p4, p5, p6, p7);
      }
    }
  } else {       // layer 2: mean over 4 heads + b3 -> out[d,32]
#pragma unroll
    for (int j = 0; j < 8; ++j) {
      acc[j] += __shfl_xor(acc[j], 4);
      acc[j] += __shfl_xor(acc[j], 8);
    }
    if (ql < 4) {
      float4 b0 = ((const float4*)bias)[ql * 2];
      float4 b1 = ((const float4*)bias)[ql * 2 + 1];
      float* orow = out + (size_t)d * 32 + ql * 8;
      *(float4*)orow = make_float4(0.25f * acc[0] + b0.x, 0.25f * acc[1] + b0.y,
                                   0.25f * acc[2] + b0.z, 0.25f * acc[3] + b0.w);
      *(float4*)(orow + 4) = make_float4(0.25f * acc[4] + b1.x, 0.25f * acc[5] + b1.y,
                                         0.25f * acc[6] + b1.z, 0.25f * acc[7] + b1.w);
    }
  }
}

extern "C" void kernel_launch(void* const* d_in, const int* in_sizes, int n_in,
                              void* d_out, int out_size, void* d_ws, size_t ws_size,
                              hipStream_t stream) {
  const float* x   = (const float*)d_in[0];
  const int*   ei  = (const int*)d_in[1];
  const float* ea  = (const float*)d_in[2];
  const int*   etp = (const int*)d_in[3];
  const float* w1  = (const float*)d_in[4];
  const float* q1  = (const float*)d_in[5];
  const float* k1  = (const float*)d_in[6];
  const float* e1  = (const float*)d_in[7];
  const float* le1 = (const float*)d_in[8];
  const float* b1  = (const float*)d_in[9];
  const float* w3  = (const float*)d_in[10];
  const float* q3  = (const float*)d_in[11];
  const float* k3  = (const float*)d_in[12];
  const float* e3  = (const float*)d_in[13];
  const float* le3 = (const float*)d_in[14];
  const float* b3  = (const float*)d_in[15];
  const int N = in_sizes[0] / 128;
  const int E = in_sizes[3];
  const int* srcp = ei;
  const int* dstp = ei + E;

  float* ws   = (float*)d_ws;
  _Float16* xwh = (_Float16*)ws;                     // 4*N*128 halfs
  float* qn   = ws + (size_t)2 * N * 128;            // 4*N*4
  float* kn   = qn + (size_t)4 * N * 4;              // 4*N*4
  float* qn2  = kn + (size_t)4 * N * 4;              // 4*N*4 (layer-2 q, from agg1)
  float* kn2  = qn2 + (size_t)4 * N * 4;             // 4*N*4 (layer-2 k, from agg1)
  float* eks1 = kn2 + (size_t)4 * N * 4;             // E*4
  float* eks3 = eks1 + (size_t)E * 4;                // E*4
  float* alph = eks3 + (size_t)E * 4;                // E*4
  float* leeb = alph + (size_t)E * 4;                // 128
  float* wqkb = leeb + 128;                          // 8192
  int* deg      = (int*)(wqkb + 8192);               // N
  int* rowst    = deg + N;                           // N+1
  int* cursor   = rowst + N + 1;                     // N
  int* bsum     = cursor + N;                        // 256
  int* boff     = bsum + 256;                        // 256
  uintptr_t pe = (uintptr_t)(boff + 256);
  pe = (pe + 15) & ~(uintptr_t)15;
  int4* es      = (int4*)pe;                         // E int4
  uintptr_t pa = (uintptr_t)(es + E);
  pa = (pa + 255) & ~(uintptr_t)255;
  unsigned short* xhi  = (unsigned short*)pa;        // N*128
  unsigned short* xlo  = xhi + (size_t)N * 128;      // N*128
  unsigned short* wF1h = xlo + (size_t)N * 128;      // 4*128*128 fragment-major
  unsigned short* wF1l = wF1h + 4 * 128 * 128;
  unsigned short* wF3h = wF1l + 4 * 128 * 128;
  unsigned short* wF3l = wF3h + 4 * 128 * 128;
  (void)ws_size; (void)n_in; (void)out_size;

  int eb   = (E + 255) / 256;
  int nb16 = (N + 15) / 16;
  int nbs  = (N + 1023) / 1024;
  int pgy  = (N + 127) / 128;
  int pjb  = 8 * pgy;                                // r(4) x half(2) x nodeblocks
  int qxb  = (N + 63) / 64;
  int cxb  = (N * 128 / 8 + 255) / 256;

  hipMemsetAsync(deg, 0, (size_t)N * sizeof(int), stream);

  // pre: hist || convx || convw(L1+L3, fragment-major) || wqk || lee
  int M = eb > cxb ? eb : cxb;
  int nAB = 2 * M;
  int preg = nAB + 512 + 32 + 1;
  pre_kernel<<<preg, 256, 0, stream>>>(dstp, deg, E, x, xhi, xlo, N * 128 / 8,
                                       w1, q1, k1, w3, q3, k3, wqkb,
                                       le1, e1, le3, e3, leeb,
                                       wF1h, wF1l, wF3h, wF3l, nAB, eb, cxb);
  scanA_kernel<<<nbs, 256, 0, stream>>>(deg, bsum, N);
  scanB_kernel<<<1, 256, 0, stream>>>(bsum, boff, rowst, nbs, N);
  scanC_kernel<<<nbs, 256, 0, stream>>>(deg, boff, rowst, cursor, N);

  // sc9: scatter || qkx(L1) || proj(L1).  9-block groups.  smem 32768.
  int scq = (eb + 3) / 4;
  int pjq = (pjb + 3) / 4;
  int g9 = scq;
  if (qxb > g9) g9 = qxb;
  if (pjq > g9) g9 = pjq;
  sc9_kernel<<<9 * g9, 256, 32768, stream>>>(srcp, dstp, etp, cursor, es, E,
                                             x, wqkb, qn, kn, N, qxb,
                                             xhi, xlo, wF1h, wF1l, xwh, pjb);

  // ek2: standalone, full occupancy for the random ea gather.
  ek2_kernel<<<eb, 256, 0, stream>>>(es, ea, leeb, eks1, eks3, E);

  // agg1: softmax-aggregate layer 1 + fused qkx(L2) -> qn2/kn2 (no hbuf).
  agg_kernel<<<nb16, 256, 0, stream>>>(es, rowst, qn, kn, eks1, alph, xwh,
                                       b1, (float*)d_out, xhi, xlo,
                                       qn2, kn2, wqkb + 4096, N, 1);

  // projL2: pure proj(L2).  smem 32768.
  projL2_kernel<<<pjb, 256, 32768, stream>>>(xhi, xlo, wF3h, wF3l, xwh, N, pjb);

  agg_kernel<<<nb16, 256, 0, stream>>>(es, rowst, qn2, kn2, eks3, alph, xwh,
                                       b3, (float*)d_out, xhi, xlo,
                                       qn2, kn2, wqkb + 4096, N, 0);
}

// Round 10
// 423.950 us; speedup vs baseline: 1.1554x; 1.1554x over previous
//
#include <hip/hip_runtime.h>

// RGATNetwork: 2x RGATConv (R=4, H=4, C=32, HC=128, F_E=16) on N=50k nodes, E=800k edges.
// R20 = R16 verbatim (best, 432us) + 2-edge-per-thread scatter unroll.
// R19 post-mortem: fusing qkx(L2) into agg's epilogue inflated agg's register/
// scheduling footprint (VGPR 28->52) and collapsed its gather BW (3.4->1.47 TB/s,
// 62->138us/dispatch) — agg's latency-bound loops are a fragile optimum; REVERTED.
// R17/R18 lessons kept: es stays int4; no wide records; ek2 standalone.
// The one change: scatter_body handles 2 edges/thread (independent atomic chains
// -> 2x in-flight atomics; scatter blocks halve, freeing issue slots for proj/qkx).

#define NEG_SLOPE 0.2f
#define SOFT_EPS 1e-16f

typedef __attribute__((ext_vector_type(8))) short bf16x8;
typedef __attribute__((ext_vector_type(4))) float f32x4;
typedef __attribute__((ext_vector_type(4))) unsigned short u16x4;
typedef __attribute__((ext_vector_type(4))) _Float16 half4;
typedef __attribute__((ext_vector_type(8))) _Float16 half8;

__device__ __forceinline__ void bf16split(float f, unsigned short& h, unsigned short& l) {
  unsigned u = __float_as_uint(f);
  unsigned r = u + 0x7FFFu + ((u >> 16) & 1u);
  h = (unsigned short)(r >> 16);
  float fh = __uint_as_float(((unsigned)h) << 16);
  float d = f - fh;
  unsigned u2 = __float_as_uint(d);
  unsigned r2 = u2 + 0x7FFFu + ((u2 >> 16) & 1u);
  l = (unsigned short)(r2 >> 16);
}

// ================= fused-preprocess bodies =================

__device__ __forceinline__ void hist_body(int id, const int* __restrict__ dst,
                                          int* __restrict__ deg, int E) {
  int e = id * 256 + (int)threadIdx.x;
  if (e < E) atomicAdd(&deg[dst[e]], 1);
}

__device__ __forceinline__ void convx_body(int id, const float* __restrict__ in,
                                           unsigned short* __restrict__ hi,
                                           unsigned short* __restrict__ lo, int total8) {
  int i = id * 256 + (int)threadIdx.x;
  if (i >= total8) return;
  const float4* p = (const float4*)in + (size_t)i * 2;
  float4 a = p[0], b = p[1];
  float v[8] = {a.x, a.y, a.z, a.w, b.x, b.y, b.z, b.w};
  bf16x8 hv, lv;
#pragma unroll
  for (int j = 0; j < 8; ++j) {
    unsigned short h, l;
    bf16split(v[j], h, l);
    hv[j] = (short)h; lv[j] = (short)l;
  }
  *(bf16x8*)(hi + (size_t)i * 8) = hv;
  *(bf16x8*)(lo + (size_t)i * 8) = lv;
}

// fragment-major w: element index = r*16384 + (((ot*4+kc)*4+q)*16 + c)*8 + j
// where o = ot*16+c, f = kc*32 + q*8 + j.
__device__ __forceinline__ void convw_body(int idx, const float* __restrict__ w1,
                                           const float* __restrict__ w3,
                                           unsigned short* __restrict__ wF1h,
                                           unsigned short* __restrict__ wF1l,
                                           unsigned short* __restrict__ wF3h,
                                           unsigned short* __restrict__ wF3l) {
  if (idx >= 131072) return;
  int L = idx >> 16;
  int rem = idx & 65535;
  int r = rem >> 14, rem2 = rem & 16383, f = rem2 >> 7, o = rem2 & 127;
  const float* w = L ? w3 : w1;
  unsigned short* dh = L ? wF3h : wF1h;
  unsigned short* dl = L ? wF3l : wF1l;
  float v = w[(r * 128 + f) * 128 + o];
  unsigned short h, l;
  bf16split(v, h, l);
  int ot = o >> 4, c = o & 15, kc = f >> 5, q = (f >> 3) & 3, j = f & 7;
  int di = r * 16384 + ((((ot * 4 + kc) * 4 + q) * 16 + c) * 8 + j);
  dh[di] = h;
  dl[di] = l;
}

__device__ __forceinline__ void wqk_body(int idx, const float* __restrict__ w1,
                                         const float* __restrict__ q1, const float* __restrict__ k1,
                                         const float* __restrict__ w3, const float* __restrict__ q3,
                                         const float* __restrict__ k3, float* __restrict__ wqk) {
  if (idx >= 8192) return;
  int L = idx >> 12, rem = idx & 4095;
  int r = rem >> 10, rem2 = rem & 1023, f = rem2 >> 3, j = rem2 & 7;
  const float* w = L ? w3 : w1;
  const float* qk = (j < 4) ? (L ? q3 : q1) : (L ? k3 : k1);
  int h = j & 3;
  const float* wrow = w + (r * 128 + f) * 128;
  float acc = 0.f;
  for (int o = 0; o < 128; ++o) acc += wrow[o] * qk[o * 4 + h];
  wqk[idx] = acc;
}

__device__ __forceinline__ void lee_body(const float* __restrict__ le1, const float* __restrict__ e1,
                                         const float* __restrict__ le3, const float* __restrict__ e3,
                                         float* __restrict__ lee) {
  int t = threadIdx.x;
  if (t >= 128) return;
  const float* le = (t < 64) ? le1 : le3;
  const float* ee = (t < 64) ? e1 : e3;
  int u = t & 63, f = u >> 2, h = u & 3;
  float acc = 0.f;
  for (int o = 0; o < 128; ++o) acc += le[f * 128 + o] * ee[o * 4 + h];
  lee[t] = acc;
}

// pre: [0,nAB): parity-interleaved hist/convx; tail: convw(512) | wqk(32) | lee(1)
__global__ __launch_bounds__(256) void pre_kernel(
    const int* __restrict__ dst, int* __restrict__ deg, int E,
    const float* __restrict__ x, unsigned short* __restrict__ xhi,
    unsigned short* __restrict__ xlo, int total8,
    const float* __restrict__ w1, const float* __restrict__ q1, const float* __restrict__ k1,
    const float* __restrict__ w3, const float* __restrict__ q3, const float* __restrict__ k3,
    float* __restrict__ wqk,
    const float* __restrict__ le1, const float* __restrict__ e1,
    const float* __restrict__ le3, const float* __restrict__ e3, float* __restrict__ lee,
    unsigned short* __restrict__ wF1h, unsigned short* __restrict__ wF1l,
    unsigned short* __restrict__ wF3h, unsigned short* __restrict__ wF3l,
    int nAB, int eb, int cxb) {
  int bid = blockIdx.x;
  if (bid < nAB) {
    int id = bid >> 1;
    if (bid & 1) {
      if (id < eb) hist_body(id, dst, deg, E);
    } else {
      if (id < cxb) convx_body(id, x, xhi, xlo, total8);
    }
  } else {
    int b2 = bid - nAB;
    if (b2 < 512) {
      convw_body(b2 * 256 + (int)threadIdx.x, w1, w3, wF1h, wF1l, wF3h, wF3l);
    } else if (b2 < 544) {
      wqk_body((b2 - 512) * 256 + (int)threadIdx.x, w1, q1, k1, w3, q3, k3, wqk);
    } else {
      lee_body(le1, e1, le3, e3, lee);
    }
  }
}

// ================= CSR scans =================

__global__ __launch_bounds__(256) void scanA_kernel(const int* __restrict__ deg,
                                                    int* __restrict__ bsum, int N) {
  int b = blockIdx.x, t = threadIdx.x;
  int base = b * 1024 + t * 4;
  int s = 0;
#pragma unroll
  for (int j = 0; j < 4; ++j) {
    int i = base + j;
    if (i < N) s += deg[i];
  }
#pragma unroll
  for (int o = 1; o < 64; o <<= 1) s += __shfl_xor(s, o);
  __shared__ int wsum[4];
  if ((t & 63) == 0) wsum[t >> 6] = s;
  __syncthreads();
  if (t == 0) bsum[b] = wsum[0] + wsum[1] + wsum[2] + wsum[3];
}

__global__ __launch_bounds__(256) void scanB_kernel(const int* __restrict__ bsum,
                                                    int* __restrict__ boff,
                                                    int* __restrict__ row_start,
                                                    int nb, int N) {
  int t = threadIdx.x;
  int v = (t < nb) ? bsum[t] : 0;
  int inc = v;
#pragma unroll
  for (int o = 1; o < 64; o <<= 1) {
    int u = __shfl_up(inc, o);
    if ((t & 63) >= o) inc += u;
  }
  __shared__ int wt[4];
  if ((t & 63) == 63) wt[t >> 6] = inc;
  __syncthreads();
  int add = 0;
  for (int wv = 0; wv < (t >> 6); ++wv) add += wt[wv];
  inc += add;
  if (t < nb) boff[t] = inc - v;
  if (t == 255) row_start[N] = inc;
}

__global__ __launch_bounds__(256) void scanC_kernel(const int* __restrict__ deg,
                                                    const int* __restrict__ boff,
                                                    int* __restrict__ row_start,
                                                    int* __restrict__ cursor, int N) {
  int b = blockIdx.x, t = threadIdx.x;
  int base = b * 1024 + t * 4;
  int d[4];
  int s = 0;
#pragma unroll
  for (int j = 0; j < 4; ++j) {
    int i = base + j;
    d[j] = (i < N) ? deg[i] : 0;
    s += d[j];
  }
  int inc = s;
#pragma unroll
  for (int o = 1; o < 64; o <<= 1) {
    int u = __shfl_up(inc, o);
    if ((t & 63) >= o) inc += u;
  }
  __shared__ int wt[4];
  if ((t & 63) == 63) wt[t >> 6] = inc;
  __syncthreads();
  int add = boff[b];
  for (int wv = 0; wv < (t >> 6); ++wv) add += wt[wv];
  int off = add + inc - s;
#pragma unroll
  for (int j = 0; j < 4; ++j) {
    int i = base + j;
    if (i < N) {
      row_start[i] = off;
      cursor[i] = off;
      off += d[j];
    }
  }
}

// ================= sc9 bodies =================

// scatter: 2 edges per thread (512 per id). The two atomic chains are independent
// -> 2x in-flight atomics per thread on the latency-bound path.
__device__ __forceinline__ void scatter_body(int id, const int* __restrict__ src,
                                             const int* __restrict__ dst,
                                             const int* __restrict__ et,
                                             int* __restrict__ cursor,
                                             int4* __restrict__ es, int E) {
  int e0 = id * 512 + (int)threadIdx.x;
  int e1 = e0 + 256;
  if (e1 < E) {
    int d0 = dst[e0], d1 = dst[e1];
    int s0 = src[e0], s1 = src[e1];
    int t0 = et[e0], t1 = et[e1];
    int p0 = atomicAdd(&cursor[d0], 1);
    int p1 = atomicAdd(&cursor[d1], 1);
    es[p0] = make_int4(s0, d0, t0, e0);
    es[p1] = make_int4(s1, d1, t1, e1);
  } else if (e0 < E) {
    int d0 = dst[e0];
    int p0 = atomicAdd(&cursor[d0], 1);
    es[p0] = make_int4(src[e0], d0, et[e0], e0);
  }
}

// qkx: qn/kn from xin via folded wqk; 64 nodes/block; smem = 16512 B (wqk stage only).
__device__ __forceinline__ void qkx_body(int nbid, char* smem, const float* __restrict__ xin,
                                         const float* __restrict__ wqk, float* __restrict__ qn,
                                         float* __restrict__ kn, int N) {
  float* swqk = (float*)smem;  // 4*1032 floats
  int t = threadIdx.x;
#pragma unroll
  for (int j = 0; j < 16; ++j) {
    int i = j * 256 + t;
    swqk[(i >> 10) * 1032 + (i & 1023)] = wqk[i];
  }
  __syncthreads();
  int nb = nbid * 64;
  int rl = t >> 2, r = t & 3;
  int n = nb + rl;
  int nc = n < N ? n : N - 1;
  const float4* xr = (const float4*)(xin + (size_t)nc * 128);
  const float* wb = swqk + r * 1032;
  float aq0 = 0, aq1 = 0, aq2 = 0, aq3 = 0;
  float ak0 = 0, ak1 = 0, ak2 = 0, ak3 = 0;
#pragma unroll 4
  for (int f4 = 0; f4 < 32; ++f4) {
    float4 xv = xr[f4];
    const float* w0 = wb + f4 * 32;
    float4 qa = *(const float4*)(w0);
    float4 ka = *(const float4*)(w0 + 4);
    float4 qb = *(const float4*)(w0 + 8);
    float4 kb = *(const float4*)(w0 + 12);
    float4 qc = *(const float4*)(w0 + 16);
    float4 kc = *(const float4*)(w0 + 20);
    float4 qd = *(const float4*)(w0 + 24);
    float4 kd = *(const float4*)(w0 + 28);
    aq0 += xv.x * qa.x + xv.y * qb.x + xv.z * qc.x + xv.w * qd.x;
    aq1 += xv.x * qa.y + xv.y * qb.y + xv.z * qc.y + xv.w * qd.y;
    aq2 += xv.x * qa.z + xv.y * qb.z + xv.z * qc.z + xv.w * qd.z;
    aq3 += xv.x * qa.w + xv.y * qb.w + xv.z * qc.w + xv.w * qd.w;
    ak0 += xv.x * ka.x + xv.y * kb.x + xv.z * kc.x + xv.w * kd.x;
    ak1 += xv.x * ka.y + xv.y * kb.y + xv.z * kc.y + xv.w * kd.y;
    ak2 += xv.x * ka.z + xv.y * kb.z + xv.z * kc.z + xv.w * kd.z;
    ak3 += xv.x * ka.w + xv.y * kb.w + xv.z * kc.w + xv.w * kd.w;
  }
  if (n < N) {
    *(float4*)(qn + ((size_t)r * N + n) * 4) = make_float4(aq0, aq1, aq2, aq3);
    *(float4*)(kn + ((size_t)r * N + n) * 4) = make_float4(ak0, ak1, ak2, ak3);
  }
}

// proj: MFMA per-relation projection; HALF-tile (4 of 8 ot) staged in 32KB LDS from
// the fragment-major global layout (contiguous 16KB copy per hi/lo).
// pid: r = pid&3, half = (pid>>2)&1, node block = (pid>>3)*128.
__device__ __forceinline__ void proj_body(int pid, char* smem,
                                          const unsigned short* __restrict__ xhi,
                                          const unsigned short* __restrict__ xlo,
                                          const unsigned short* __restrict__ wFh,
                                          const unsigned short* __restrict__ wFl,
                                          _Float16* __restrict__ xwh, int N) {
  bf16x8* wl_h = (bf16x8*)smem;   // 1024 units, 16KB
  bf16x8* wl_l = wl_h + 1024;     // 16KB
  int r = pid & 3;
  int h0 = (pid >> 2) & 1;
  int nb = (pid >> 3) * 128;
  int t = threadIdx.x;
  const bf16x8* srcH = (const bf16x8*)(wFh + r * 16384) + h0 * 1024;
  const bf16x8* srcL = (const bf16x8*)(wFl + r * 16384) + h0 * 1024;
#pragma unroll
  for (int j = 0; j < 4; ++j) {
    int i = j * 256 + t;
    wl_h[i] = srcH[i];
    wl_l[i] = srcL[i];
  }
  __syncthreads();

  int wv = t >> 6;
  int lane = t & 63;
  int c = lane & 15, q = lane >> 4;
  int nodebase = nb + wv * 32;
  int n0 = nodebase + c;
  int n1 = nodebase + 16 + c;
  int n0c = n0 < N ? n0 : N - 1;
  int n1c = n1 < N ? n1 : N - 1;

  f32x4 acc[4][2];
#pragma unroll
  for (int ot = 0; ot < 4; ++ot)
#pragma unroll
    for (int nt = 0; nt < 2; ++nt) acc[ot][nt] = (f32x4){0.f, 0.f, 0.f, 0.f};

  bf16x8 xb[2][4];
  {
    int k0 = q * 8;
    xb[0][0] = *(const bf16x8*)(xhi + (size_t)n0c * 128 + k0);
    xb[0][1] = *(const bf16x8*)(xlo + (size_t)n0c * 128 + k0);
    xb[0][2] = *(const bf16x8*)(xhi + (size_t)n1c * 128 + k0);
    xb[0][3] = *(const bf16x8*)(xlo + (size_t)n1c * 128 + k0);
  }
#pragma unroll
  for (int kc = 0; kc < 4; ++kc) {
    if (kc < 3) {
      int k0 = (kc + 1) * 32 + q * 8;
      xb[(kc + 1) & 1][0] = *(const bf16x8*)(xhi + (size_t)n0c * 128 + k0);
      xb[(kc + 1) & 1][1] = *(const bf16x8*)(xlo + (size_t)n0c * 128 + k0);
      xb[(kc + 1) & 1][2] = *(const bf16x8*)(xhi + (size_t)n1c * 128 + k0);
      xb[(kc + 1) & 1][3] = *(const bf16x8*)(xlo + (size_t)n1c * 128 + k0);
    }
    bf16x8 b0h = xb[kc & 1][0], b0l = xb[kc & 1][1];
    bf16x8 b1h = xb[kc & 1][2], b1l = xb[kc & 1][3];
#pragma unroll
    for (int ot = 0; ot < 4; ++ot) {
      int fi = ((ot * 4 + kc) * 4 + q) * 16 + c;
      bf16x8 ah = wl_h[fi];
      bf16x8 al = wl_l[fi];
      acc[ot][0] = __builtin_amdgcn_mfma_f32_16x16x32_bf16(ah, b0h, acc[ot][0], 0, 0, 0);
      acc[ot][0] = __builtin_amdgcn_mfma_f32_16x16x32_bf16(ah, b0l, acc[ot][0], 0, 0, 0);
      acc[ot][0] = __builtin_amdgcn_mfma_f32_16x16x32_bf16(al, b0h, acc[ot][0], 0, 0, 0);
      acc[ot][1] = __builtin_amdgcn_mfma_f32_16x16x32_bf16(ah, b1h, acc[ot][1], 0, 0, 0);
      acc[ot][1] = __builtin_amdgcn_mfma_f32_16x16x32_bf16(ah, b1l, acc[ot][1], 0, 0, 0);
      acc[ot][1] = __builtin_amdgcn_mfma_f32_16x16x32_bf16(al, b1h, acc[ot][1], 0, 0, 0);
    }
  }

#pragma unroll
  for (int nt = 0; nt < 2; ++nt) {
    int n = nodebase + nt * 16 + c;
    if (n < N) {
      _Float16* basep = xwh + ((size_t)r * N + n) * 128 + h0 * 64 + q * 4;
#pragma unroll
      for (int ot = 0; ot < 4; ++ot) {
        f32x4 a = acc[ot][nt];
        half4 hv;
        hv[0] = (_Float16)a.x; hv[1] = (_Float16)a.y;
        hv[2] = (_Float16)a.z; hv[3] = (_Float16)a.w;
        *(half4*)(basep + ot * 16) = hv;
      }
    }
  }
}

// sc9: groups of 9 blocks = 4 scatter + 1 qkx(L1) + 4 proj(L1).  smem = 32768 B.
__global__ __launch_bounds__(256) void sc9_kernel(
    const int* __restrict__ src, const int* __restrict__ dst, const int* __restrict__ et,
    int* __restrict__ cursor, int4* __restrict__ es, int E,
    const float* __restrict__ xin, const float* __restrict__ wqk,
    float* __restrict__ qn, float* __restrict__ kn, int N, int qxb,
    const unsigned short* __restrict__ xhi, const unsigned short* __restrict__ xlo,
    const unsigned short* __restrict__ wFh, const unsigned short* __restrict__ wFl,
    _Float16* __restrict__ xwh, int pjb) {
  extern __shared__ char smem[];
  int bid = blockIdx.x;
  int g = bid / 9, r9 = bid - g * 9;
  if (r9 < 4) {
    scatter_body(g * 4 + r9, src, dst, et, cursor, es, E);
  } else if (r9 == 4) {
    if (g < qxb) qkx_body(g, smem, xin, wqk, qn, kn, N);
  } else {
    int id = g * 4 + (r9 - 5);
    if (id < pjb) proj_body(id, smem, xhi, xlo, wFh, wFl, xwh, N);
  }
}

// ================= ek2 (standalone) =================

__global__ __launch_bounds__(256) void ek2_kernel(
    const int4* __restrict__ es, const float* __restrict__ ea,
    const float* __restrict__ lee, float* __restrict__ eks1,
    float* __restrict__ eks3, int E) {
  __shared__ float sl[128];
  if (threadIdx.x < 128) sl[threadIdx.x] = lee[threadIdx.x];
  __syncthreads();
  int i = blockIdx.x * 256 + (int)threadIdx.x;
  if (i >= E) return;
  int eid = es[i].w;
  const float4* a4 = (const float4*)(ea + (size_t)eid * 16);
  float a1[4] = {0, 0, 0, 0}, a3[4] = {0, 0, 0, 0};
#pragma unroll
  for (int ii = 0; ii < 4; ++ii) {
    float4 v = a4[ii];
    int f = ii * 4;
#pragma unroll
    for (int h = 0; h < 4; ++h) {
      a1[h] += v.x * sl[f * 4 + h] + v.y * sl[(f + 1) * 4 + h] +
               v.z * sl[(f + 2) * 4 + h] + v.w * sl[(f + 3) * 4 + h];
      a3[h] += v.x * sl[64 + f * 4 + h] + v.y * sl[64 + (f + 1) * 4 + h] +
               v.z * sl[64 + (f + 2) * 4 + h] + v.w * sl[64 + (f + 3) * 4 + h];
    }
  }
  *(float4*)(eks1 + (size_t)i * 4) = make_float4(a1[0], a1[1], a1[2], a1[3]);
  *(float4*)(eks3 + (size_t)i * 4) = make_float4(a3[0], a3[1], a3[2], a3[3]);
}

// p2: groups of 5 blocks = 4 proj(L2) + 1 qkx(L2).  smem = 32768 B.
__global__ __launch_bounds__(256) void p2_kernel(
    const unsigned short* __restrict__ xhi, const unsigned short* __restrict__ xlo,
    const unsigned short* __restrict__ wFh, const unsigned short* __restrict__ wFl,
    _Float16* __restrict__ xwh, int N,
    const float* __restrict__ xin, const float* __restrict__ wqk,
    float* __restrict__ qn, float* __restrict__ kn, int pjb, int qxb) {
  extern __shared__ char smem[];
  int bid = blockIdx.x;
  int g = bid / 5, r5 = bid - g * 5;
  if (r5 == 4) {
    if (g < qxb) qkx_body(g, smem, xin, wqk, qn, kn, N);
  } else {
    int id = g * 4 + r5;
    if (id < pjb) proj_body(id, smem, xhi, xlo, wFh, wFl, xwh, N);
  }
}

// ================= fused softmax-aggregate =================

__device__ __forceinline__ float4 edge_alpha(const int4* __restrict__ es,
                                             const float* __restrict__ qn,
                                             const float* __restrict__ kn,
                                             const float* __restrict__ eks,
                                             int i, int d, int N) {
  int4 v = es[i];
  float4 kv = *(const float4*)(kn + (v.z * N + v.x) * 4);
  float4 ev = ((const float4*)eks)[i];
  float4 q4 = *(const float4*)(qn + (v.z * N + d) * 4);
  float4 a = make_float4(q4.x + kv.x + ev.x, q4.y + kv.y + ev.y,
                         q4.z + kv.z + ev.z, q4.w + kv.w + ev.w);
  a.x = a.x > 0.f ? a.x : NEG_SLOPE * a.x;
  a.y = a.y > 0.f ? a.y : NEG_SLOPE * a.y;
  a.z = a.z > 0.f ? a.z : NEG_SLOPE * a.z;
  a.w = a.w > 0.f ? a.w : NEG_SLOPE * a.w;
  return a;
}

__device__ __forceinline__ float4 max4(float4 a, float4 b) {
  return make_float4(fmaxf(a.x, b.x), fmaxf(a.y, b.y), fmaxf(a.z, b.z), fmaxf(a.w, b.w));
}

// One 16-lane quarter per dst. Sweep A: branchless clamped 4-chain loads (deg<=64),
// cndmask validity. Pass 2: 4 independent edge chains per iteration.
__global__ __launch_bounds__(256) void agg_kernel(
    const int4* __restrict__ es, const int* __restrict__ row_start,
    const float* __restrict__ qn, const float* __restrict__ kn,
    const float* __restrict__ eks, float* __restrict__ alpha_s,
    const _Float16* __restrict__ xwh, const float* __restrict__ bias,
    float* __restrict__ out, unsigned short* __restrict__ xhi,
    unsigned short* __restrict__ xlo, int N, int concat) {
  int d = blockIdx.x * 16 + (threadIdx.x >> 4);
  if (d >= N) return;
  int ql = threadIdx.x & 15;
  int rs = row_start[d], re = row_start[d + 1];
  int deg = re - rs;
  int h = ql >> 2;

  float acc[8];
#pragma unroll
  for (int j = 0; j < 8; ++j) acc[j] = 0.f;
  float rden = 0.f;

  if (deg > 0) {
    float4 m = make_float4(-1e30f, -1e30f, -1e30f, -1e30f);
    float4 ar0 = m, ar1 = m, ar2 = m, ar3 = m;
    bool fast = (deg <= 64);
    bool v0 = ql < deg, v1 = 16 + ql < deg, v2 = 32 + ql < deg, v3 = 48 + ql < deg;
    if (fast) {
      int dm1 = deg - 1;
      int o0 = v0 ? ql : dm1;
      int o1 = v1 ? 16 + ql : dm1;
      int o2 = v2 ? 32 + ql : dm1;
      int o3 = v3 ? 48 + ql : dm1;
      float4 a0 = edge_alpha(es, qn, kn, eks, rs + o0, d, N);
      float4 a1 = edge_alpha(es, qn, kn, eks, rs + o1, d, N);
      float4 a2 = edge_alpha(es, qn, kn, eks, rs + o2, d, N);
      float4 a3 = edge_alpha(es, qn, kn, eks, rs + o3, d, N);
      if (v0) { ar0 = a0; m = max4(m, a0); }
      if (v1) { ar1 = a1; m = max4(m, a1); }
      if (v2) { ar2 = a2; m = max4(m, a2); }
      if (v3) { ar3 = a3; m = max4(m, a3); }
    } else {
      for (int i = rs + ql; i < re; i += 16) {
        float4 a = edge_alpha(es, qn, kn, eks, i, d, N);
        ((float4*)alpha_s)[i] = a;
        m = max4(m, a);
      }
    }
#pragma unroll
    for (int o = 1; o < 16; o <<= 1) {
      m.x = fmaxf(m.x, __shfl_xor(m.x, o));
      m.y = fmaxf(m.y, __shfl_xor(m.y, o));
      m.z = fmaxf(m.z, __shfl_xor(m.z, o));
      m.w = fmaxf(m.w, __shfl_xor(m.w, o));
    }

    float4 s = make_float4(0.f, 0.f, 0.f, 0.f);
    if (fast) {
#define SWEEPB(V, AR, OFF)                                                   \
      if (V) {                                                               \
        float4 e4 = make_float4(__expf(AR.x - m.x), __expf(AR.y - m.y),      \
                                __expf(AR.z - m.z), __expf(AR.w - m.w));     \
        ((float4*)alpha_s)[rs + OFF + ql] = e4;                              \
        s.x += e4.x; s.y += e4.y; s.z += e4.z; s.w += e4.w;                  \
      }
      SWEEPB(v0, ar0, 0)
      SWEEPB(v1, ar1, 16)
      SWEEPB(v2, ar2, 32)
      SWEEPB(v3, ar3, 48)
#undef SWEEPB
    } else {
      for (int i = rs + ql; i < re; i += 16) {
        float4 a = ((const float4*)alpha_s)[i];
        float4 e4 = make_float4(__expf(a.x - m.x), __expf(a.y - m.y),
                                __expf(a.z - m.z), __expf(a.w - m.w));
        ((float4*)alpha_s)[i] = e4;
        s.x += e4.x; s.y += e4.y; s.z += e4.z; s.w += e4.w;
      }
    }
#pragma unroll
    for (int o = 1; o < 16; o <<= 1) {
      s.x += __shfl_xor(s.x, o); s.y += __shfl_xor(s.y, o);
      s.z += __shfl_xor(s.z, o); s.w += __shfl_xor(s.w, o);
    }
    float smh = (h == 0) ? s.x : (h == 1) ? s.y : (h == 2) ? s.z : s.w;
    rden = 1.f / (smh + SOFT_EPS);

    // pass 2: 4 independent edge chains per iteration
    int e = rs;
    for (; e + 4 <= re; e += 4) {
      int4 a0 = es[e];
      int4 a1 = es[e + 1];
      int4 a2 = es[e + 2];
      int4 a3 = es[e + 3];
      float w0 = alpha_s[e * 4 + h];
      float w1 = alpha_s[(e + 1) * 4 + h];
      float w2 = alpha_s[(e + 2) * 4 + h];
      float w3 = alpha_s[(e + 3) * 4 + h];
      half8 x0 = *(const half8*)(xwh + (a0.z * N + a0.x) * 128 + ql * 8);
      half8 x1 = *(const half8*)(xwh + (a1.z * N + a1.x) * 128 + ql * 8);
      half8 x2 = *(const half8*)(xwh + (a2.z * N + a2.x) * 128 + ql * 8);
      half8 x3 = *(const half8*)(xwh + (a3.z * N + a3.x) * 128 + ql * 8);
#pragma unroll
      for (int j = 0; j < 8; ++j) {
        acc[j] = fmaf((float)x0[j], w0, acc[j]);
        acc[j] = fmaf((float)x1[j], w1, acc[j]);
        acc[j] = fmaf((float)x2[j], w2, acc[j]);
        acc[j] = fmaf((float)x3[j], w3, acc[j]);
      }
    }
    for (; e < re; ++e) {
      int4 a0 = es[e];
      float w0 = alpha_s[e * 4 + h];
      half8 x0 = *(const half8*)(xwh + (a0.z * N + a0.x) * 128 + ql * 8);
#pragma unroll
      for (int j = 0; j < 8; ++j) acc[j] = fmaf((float)x0[j], w0, acc[j]);
    }
  }
#pragma unroll
  for (int j = 0; j < 8; ++j) acc[j] *= rden;

  if (concat) {  // layer 1: relu(agg+b1) -> hbuf + fused bf16 split for layer-2 proj
    float4 b0 = ((const float4*)bias)[ql * 2];
    float4 b1 = ((const float4*)bias)[ql * 2 + 1];
    float v[8] = {acc[0] + b0.x, acc[1] + b0.y, acc[2] + b0.z, acc[3] + b0.w,
                  acc[4] + b1.x, acc[5] + b1.y, acc[6] + b1.z, acc[7] + b1.w};
    u16x4 hv0, lv0, hv1, lv1;
#pragma unroll
    for (int j = 0; j < 8; ++j) {
      v[j] = v[j] > 0.f ? v[j] : 0.f;
      unsigned short hh, ll;
      bf16split(v[j], hh, ll);
      if (j < 4) { hv0[j] = hh; lv0[j] = ll; }
      else { hv1[j - 4] = hh; lv1[j - 4] = ll; }
    }
    float* orow = out + (size_t)d * 128 + ql * 8;
    *(float4*)orow = make_float4(v[0], v[1], v[2], v[3]);
    *(float4*)(orow + 4) = make_float4(v[4], v[5], v[6], v[7]);
    *(u16x4*)(xhi + (size_t)d * 128 + ql * 8) = hv0;
    *(u16x4*)(xhi + (size_t)d * 128 + ql * 8 + 4) = hv1;
    *(u16x4*)(xlo + (size_t)d * 128 + ql * 8) = lv0;
    *(u16x4*)(xlo + (size_t)d * 128 + ql * 8 + 4) = lv1;
  } else {       // layer 2: mean over 4 heads + b3 -> out[d,32]
#pragma unroll
    for (int j = 0; j < 8; ++j) {
      acc[j] += __shfl_xor(acc[j], 4);
      acc[j] += __shfl_xor(acc[j], 8);
    }
    if (ql < 4) {
      float4 b0 = ((const float4*)bias)[ql * 2];
      float4 b1 = ((const float4*)bias)[ql * 2 + 1];
      float* orow = out + (size_t)d * 32 + ql * 8;
      *(float4*)orow = make_float4(0.25f * acc[0] + b0.x, 0.25f * acc[1] + b0.y,
                                   0.25f * acc[2] + b0.z, 0.25f * acc[3] + b0.w);
      *(float4*)(orow + 4) = make_float4(0.25f * acc[4] + b1.x, 0.25f * acc[5] + b1.y,
                                         0.25f * acc[6] + b1.z, 0.25f * acc[7] + b1.w);
    }
  }
}

extern "C" void kernel_launch(void* const* d_in, const int* in_sizes, int n_in,
                              void* d_out, int out_size, void* d_ws, size_t ws_size,
                              hipStream_t stream) {
  const float* x   = (const float*)d_in[0];
  const int*   ei  = (const int*)d_in[1];
  const float* ea  = (const float*)d_in[2];
  const int*   etp = (const int*)d_in[3];
  const float* w1  = (const float*)d_in[4];
  const float* q1  = (const float*)d_in[5];
  const float* k1  = (const float*)d_in[6];
  const float* e1  = (const float*)d_in[7];
  const float* le1 = (const float*)d_in[8];
  const float* b1  = (const float*)d_in[9];
  const float* w3  = (const float*)d_in[10];
  const float* q3  = (const float*)d_in[11];
  const float* k3  = (const float*)d_in[12];
  const float* e3  = (const float*)d_in[13];
  const float* le3 = (const float*)d_in[14];
  const float* b3  = (const float*)d_in[15];
  const int N = in_sizes[0] / 128;
  const int E = in_sizes[3];
  const int* srcp = ei;
  const int* dstp = ei + E;

  float* ws   = (float*)d_ws;
  _Float16* xwh = (_Float16*)ws;                     // 4*N*128 halfs
  float* qn   = ws + (size_t)2 * N * 128;            // 4*N*4
  float* kn   = qn + (size_t)4 * N * 4;              // 4*N*4
  float* eks1 = kn + (size_t)4 * N * 4;              // E*4
  float* eks3 = eks1 + (size_t)E * 4;                // E*4
  float* alph = eks3 + (size_t)E * 4;                // E*4
  float* hbuf = alph + (size_t)E * 4;                // N*128
  float* leeb = hbuf + (size_t)N * 128;              // 128
  float* wqkb = leeb + 128;                          // 8192
  int* deg      = (int*)(wqkb + 8192);               // N
  int* rowst    = deg + N;                           // N+1
  int* cursor   = rowst + N + 1;                     // N
  int* bsum     = cursor + N;                        // 256
  int* boff     = bsum + 256;                        // 256
  uintptr_t pe = (uintptr_t)(boff + 256);
  pe = (pe + 15) & ~(uintptr_t)15;
  int4* es      = (int4*)pe;                         // E int4
  uintptr_t pa = (uintptr_t)(es + E);
  pa = (pa + 255) & ~(uintptr_t)255;
  unsigned short* xhi  = (unsigned short*)pa;        // N*128
  unsigned short* xlo  = xhi + (size_t)N * 128;      // N*128
  unsigned short* wF1h = xlo + (size_t)N * 128;      // 4*128*128 fragment-major
  unsigned short* wF1l = wF1h + 4 * 128 * 128;
  unsigned short* wF3h = wF1l + 4 * 128 * 128;
  unsigned short* wF3l = wF3h + 4 * 128 * 128;
  (void)ws_size; (void)n_in; (void)out_size;

  int eb   = (E + 255) / 256;
  int nb16 = (N + 15) / 16;
  int nbs  = (N + 1023) / 1024;
  int pgy  = (N + 127) / 128;
  int pjb  = 8 * pgy;                                // r(4) x half(2) x nodeblocks
  int qxb  = (N + 63) / 64;
  int cxb  = (N * 128 / 8 + 255) / 256;

  hipMemsetAsync(deg, 0, (size_t)N * sizeof(int), stream);

  // pre: hist || convx || convw(L1+L3, fragment-major) || wqk || lee
  int M = eb > cxb ? eb : cxb;
  int nAB = 2 * M;
  int preg = nAB + 512 + 32 + 1;
  pre_kernel<<<preg, 256, 0, stream>>>(dstp, deg, E, x, xhi, xlo, N * 128 / 8,
                                       w1, q1, k1, w3, q3, k3, wqkb,
                                       le1, e1, le3, e3, leeb,
                                       wF1h, wF1l, wF3h, wF3l, nAB, eb, cxb);
  scanA_kernel<<<nbs, 256, 0, stream>>>(deg, bsum, N);
  scanB_kernel<<<1, 256, 0, stream>>>(bsum, boff, rowst, nbs, N);
  scanC_kernel<<<nbs, 256, 0, stream>>>(deg, boff, rowst, cursor, N);

  // sc9: scatter(2-edge) || qkx(L1) || proj(L1).  9-block groups.  smem 32768.
  int scq = (E + 2047) / 2048;                       // 4 scatter blocks x 512 edges/group
  int pjq = (pjb + 3) / 4;
  int g9 = scq;
  if (qxb > g9) g9 = qxb;
  if (pjq > g9) g9 = pjq;
  sc9_kernel<<<9 * g9, 256, 32768, stream>>>(srcp, dstp, etp, cursor, es, E,
                                             x, wqkb, qn, kn, N, qxb,
                                             xhi, xlo, wF1h, wF1l, xwh, pjb);

  // ek2: standalone, full occupancy for the random ea gather.
  ek2_kernel<<<eb, 256, 0, stream>>>(es, ea, leeb, eks1, eks3, E);

  agg_kernel<<<nb16, 256, 0, stream>>>(es, rowst, qn, kn, eks1, alph, xwh,
                                       b1, hbuf, xhi, xlo, N, 1);

  // p2: proj(L2) || qkx(L2).  5-block groups = 4 proj + 1 qkx.  smem 32768.
  int p2grp = pjq > qxb ? pjq : qxb;
  p2_kernel<<<5 * p2grp, 256, 32768, stream>>>(xhi, xlo, wF3h, wF3l, xwh, N,
                                               hbuf, wqkb + 4096, qn, kn, pjb, qxb);

  agg_kernel<<<nb16, 256, 0, stream>>>(es, rowst, qn, kn, eks3, alph, xwh,
                                       b3, (float*)d_out, xhi, xlo, N, 0);
}